// Round 1
// baseline (3258.859 us; speedup 1.0000x reference)
//
#include <hip/hip_runtime.h>
#include <math.h>

#define N_NODES 100000
#define N_EDGES 3200000
#define IN_FEAT 256
#define HEADS 2
#define NC 8
#define FH 16               // HEADS*NC
#define NEG_SLOPE 0.2f
#define EPSF 1e-15f

// Order-preserving float->uint encoding for atomicMax on floats.
__device__ __forceinline__ unsigned int fenc(float f) {
    unsigned int u = __float_as_uint(f);
    return (u & 0x80000000u) ? ~u : (u | 0x80000000u);
}
__device__ __forceinline__ float fdec(unsigned int u) {
    u = (u & 0x80000000u) ? (u & 0x7FFFFFFFu) : ~u;
    return __uint_as_float(u);
}

// Kernel 1: per-node logmap0 + feat = h@W, res = h@W_res, el/er attn dots.
__global__ __launch_bounds__(256) void k_node(
        const float* __restrict__ x, const float* __restrict__ W,
        const float* __restrict__ Wres, const float* __restrict__ attn_l,
        const float* __restrict__ attn_r,
        float* __restrict__ feat, float* __restrict__ res,
        float* __restrict__ el, float* __restrict__ er) {
    __shared__ float sW[IN_FEAT][FH];
    __shared__ float sWr[IN_FEAT][FH];
    for (int i = threadIdx.x; i < IN_FEAT * FH; i += 256) {
        sW[i / FH][i % FH]  = W[i];
        sWr[i / FH][i % FH] = Wres[i];
    }
    __syncthreads();
    int n = blockIdx.x * blockDim.x + threadIdx.x;
    if (n >= N_NODES) return;
    const float* xr = x + (size_t)n * IN_FEAT;

    // pass 1: squared norm
    float ss = 0.f;
    for (int r = 0; r < IN_FEAT; r += 4) {
        float4 v = *(const float4*)(xr + r);
        ss += v.x * v.x + v.y * v.y + v.z * v.z + v.w * v.w;
    }
    float norm = fmaxf(sqrtf(ss), EPSF);
    float z = fminf(fmaxf(norm, -1.f + 1e-7f), 1.f - 1e-7f);
    float at = 0.5f * (log1pf(z) - log1pf(-z));  // artanh(clipped)
    float scale = at / norm;

    // pass 2: h @ [W | W_res]  (W rows broadcast from LDS)
    float acc[2 * FH];
    #pragma unroll
    for (int k = 0; k < 2 * FH; k++) acc[k] = 0.f;
    for (int r = 0; r < IN_FEAT; r += 4) {
        float4 v = *(const float4*)(xr + r);
        float hv[4] = {scale * v.x, scale * v.y, scale * v.z, scale * v.w};
        #pragma unroll
        for (int j = 0; j < 4; j++) {
            #pragma unroll
            for (int k = 0; k < FH; k++) {
                acc[k]      = fmaf(hv[j], sW[r + j][k],  acc[k]);
                acc[FH + k] = fmaf(hv[j], sWr[r + j][k], acc[FH + k]);
            }
        }
    }

    size_t o = (size_t)n * FH;
    float elh[HEADS] = {0.f, 0.f}, erh[HEADS] = {0.f, 0.f};
    #pragma unroll
    for (int h = 0; h < HEADS; h++) {
        #pragma unroll
        for (int c = 0; c < NC; c++) {
            float f = acc[h * NC + c];
            feat[o + h * NC + c] = f;
            res[o + h * NC + c]  = acc[FH + h * NC + c];
            elh[h] = fmaf(f, attn_l[h * NC + c], elh[h]);
            erh[h] = fmaf(f, attn_r[h * NC + c], erh[h]);
        }
    }
    el[n * 2 + 0] = elh[0]; el[n * 2 + 1] = elh[1];
    er[n * 2 + 0] = erh[0]; er[n * 2 + 1] = erh[1];
}

// Kernel 2: init m/denom/S
__global__ void k_init(unsigned int* __restrict__ menc,
                       float* __restrict__ denom, float* __restrict__ S) {
    int i = blockIdx.x * blockDim.x + threadIdx.x;
    if (i < N_NODES * FH) S[i] = 0.f;
    if (i < N_NODES * HEADS) {
        denom[i] = 0.f;
        menc[i] = fenc(-INFINITY);
    }
}

// Kernel 3: segment max over incoming edges (encoded atomicMax)
__global__ __launch_bounds__(256) void k_max(
        const int* __restrict__ ei, const float* __restrict__ el,
        const float* __restrict__ er, unsigned int* __restrict__ menc) {
    int e = blockIdx.x * blockDim.x + threadIdx.x;
    if (e >= N_EDGES) return;
    int s = ei[e], d = ei[N_EDGES + e];
    #pragma unroll
    for (int h = 0; h < HEADS; h++) {
        float v = el[s * 2 + h] + er[d * 2 + h];
        v = v >= 0.f ? v : NEG_SLOPE * v;
        atomicMax(&menc[d * 2 + h], fenc(v));
    }
}

// Kernel 4: accumulate denom and unnormalized messages
__global__ __launch_bounds__(256) void k_acc(
        const int* __restrict__ ei, const float* __restrict__ el,
        const float* __restrict__ er, const unsigned int* __restrict__ menc,
        const float* __restrict__ feat,
        float* __restrict__ denom, float* __restrict__ S) {
    int e = blockIdx.x * blockDim.x + threadIdx.x;
    if (e >= N_EDGES) return;
    int s = ei[e], d = ei[N_EDGES + e];
    #pragma unroll
    for (int h = 0; h < HEADS; h++) {
        float v = el[s * 2 + h] + er[d * 2 + h];
        v = v >= 0.f ? v : NEG_SLOPE * v;
        float w = expf(v - fdec(menc[d * 2 + h]));
        atomicAdd(&denom[d * 2 + h], w);
        #pragma unroll
        for (int c = 0; c < NC; c++) {
            atomicAdd(&S[(size_t)d * FH + h * NC + c],
                      w * feat[(size_t)s * FH + h * NC + c]);
        }
    }
}

// Kernel 5: rst = S/denom + res + bias; mean over heads
__global__ void k_fin(const float* __restrict__ S, const float* __restrict__ denom,
                      const float* __restrict__ res, const float* __restrict__ bias,
                      float* __restrict__ out) {
    int n = blockIdx.x * blockDim.x + threadIdx.x;
    if (n >= N_NODES) return;
    #pragma unroll
    for (int c = 0; c < NC; c++) {
        float a = 0.f;
        #pragma unroll
        for (int h = 0; h < HEADS; h++) {
            float r = S[(size_t)n * FH + h * NC + c] / fmaxf(denom[n * 2 + h], EPSF)
                    + res[(size_t)n * FH + h * NC + c] + bias[h * NC + c];
            a += r;
        }
        out[(size_t)n * NC + c] = a * 0.5f;
    }
}

extern "C" void kernel_launch(void* const* d_in, const int* in_sizes, int n_in,
                              void* d_out, int out_size, void* d_ws, size_t ws_size,
                              hipStream_t stream) {
    const float* x      = (const float*)d_in[0];
    const int*   ei     = (const int*)d_in[1];
    const float* W      = (const float*)d_in[2];
    const float* attn_l = (const float*)d_in[3];
    const float* attn_r = (const float*)d_in[4];
    const float* bias   = (const float*)d_in[5];
    const float* Wres   = (const float*)d_in[6];
    float* out = (float*)d_out;

    char* ws = (char*)d_ws;
    const size_t szNF = (size_t)N_NODES * FH * sizeof(float);     // 6.4 MB
    const size_t szNH = (size_t)N_NODES * HEADS * sizeof(float);  // 0.8 MB
    float* feat        = (float*)(ws);
    float* res         = (float*)(ws + szNF);
    float* el          = (float*)(ws + 2 * szNF);
    float* er          = (float*)(ws + 2 * szNF + szNH);
    unsigned int* menc = (unsigned int*)(ws + 2 * szNF + 2 * szNH);
    float* denom       = (float*)(ws + 2 * szNF + 3 * szNH);
    float* S           = (float*)(ws + 2 * szNF + 4 * szNH);

    k_node<<<(N_NODES + 255) / 256, 256, 0, stream>>>(x, W, Wres, attn_l, attn_r,
                                                      feat, res, el, er);
    k_init<<<(N_NODES * FH + 255) / 256, 256, 0, stream>>>(menc, denom, S);
    k_max<<<(N_EDGES + 255) / 256, 256, 0, stream>>>(ei, el, er, menc);
    k_acc<<<(N_EDGES + 255) / 256, 256, 0, stream>>>(ei, el, er, menc, feat, denom, S);
    k_fin<<<(N_NODES + 255) / 256, 256, 0, stream>>>(S, denom, res, bias, out);
}

// Round 2
// 767.699 us; speedup vs baseline: 4.2450x; 4.2450x over previous
//
#include <hip/hip_runtime.h>
#include <math.h>

#define N_NODES 100000
#define N_EDGES 3200000
#define IN_FEAT 256
#define HEADS 2
#define NC 8
#define FH 16               // HEADS*NC
#define NEG_SLOPE 0.2f
#define EPSF 1e-15f

#define SCAN_THREADS 1024
#define SCAN_CHUNK ((N_NODES + SCAN_THREADS - 1) / SCAN_THREADS)  // 98

// Kernel 1: per-node logmap0 + feat = h@W, res = h@W_res, el/er attn dots.
__global__ __launch_bounds__(256) void k_node(
        const float* __restrict__ x, const float* __restrict__ W,
        const float* __restrict__ Wres, const float* __restrict__ attn_l,
        const float* __restrict__ attn_r,
        float* __restrict__ feat, float* __restrict__ res,
        float* __restrict__ el, float* __restrict__ er) {
    __shared__ float sW[IN_FEAT][FH];
    __shared__ float sWr[IN_FEAT][FH];
    for (int i = threadIdx.x; i < IN_FEAT * FH; i += 256) {
        sW[i / FH][i % FH]  = W[i];
        sWr[i / FH][i % FH] = Wres[i];
    }
    __syncthreads();
    int n = blockIdx.x * blockDim.x + threadIdx.x;
    if (n >= N_NODES) return;
    const float* xr = x + (size_t)n * IN_FEAT;

    // pass 1: squared norm
    float ss = 0.f;
    for (int r = 0; r < IN_FEAT; r += 4) {
        float4 v = *(const float4*)(xr + r);
        ss += v.x * v.x + v.y * v.y + v.z * v.z + v.w * v.w;
    }
    float norm = fmaxf(sqrtf(ss), EPSF);
    float z = fminf(fmaxf(norm, -1.f + 1e-7f), 1.f - 1e-7f);
    float at = 0.5f * (log1pf(z) - log1pf(-z));  // artanh(clipped)
    float scale = at / norm;

    // pass 2: h @ [W | W_res]
    float acc[2 * FH];
    #pragma unroll
    for (int k = 0; k < 2 * FH; k++) acc[k] = 0.f;
    for (int r = 0; r < IN_FEAT; r += 4) {
        float4 v = *(const float4*)(xr + r);
        float hv[4] = {scale * v.x, scale * v.y, scale * v.z, scale * v.w};
        #pragma unroll
        for (int j = 0; j < 4; j++) {
            #pragma unroll
            for (int k = 0; k < FH; k++) {
                acc[k]      = fmaf(hv[j], sW[r + j][k],  acc[k]);
                acc[FH + k] = fmaf(hv[j], sWr[r + j][k], acc[FH + k]);
            }
        }
    }

    size_t o = (size_t)n * FH;
    float elh[HEADS] = {0.f, 0.f}, erh[HEADS] = {0.f, 0.f};
    #pragma unroll
    for (int h = 0; h < HEADS; h++) {
        #pragma unroll
        for (int c = 0; c < NC; c++) {
            float f = acc[h * NC + c];
            feat[o + h * NC + c] = f;
            res[o + h * NC + c]  = acc[FH + h * NC + c];
            elh[h] = fmaf(f, attn_l[h * NC + c], elh[h]);
            erh[h] = fmaf(f, attn_r[h * NC + c], erh[h]);
        }
    }
    el[n * 2 + 0] = elh[0]; el[n * 2 + 1] = elh[1];
    er[n * 2 + 0] = erh[0]; er[n * 2 + 1] = erh[1];
}

// Kernel 2: histogram of destination degrees (counts pre-zeroed by memset)
__global__ __launch_bounds__(256) void k_hist(const int* __restrict__ ei,
                                              int* __restrict__ cnt) {
    int e = blockIdx.x * blockDim.x + threadIdx.x;
    if (e >= N_EDGES) return;
    atomicAdd(&cnt[ei[N_EDGES + e]], 1);
}

// Kernel 3: single-block exclusive prefix scan of degree counts.
// Writes base[0..N] and cursor[0..N-1] (= base copy for the scatter pass).
__global__ __launch_bounds__(SCAN_THREADS) void k_scan(
        const int* __restrict__ cnt, int* __restrict__ base,
        int* __restrict__ cursor) {
    __shared__ int sPart[SCAN_THREADS];
    int t = threadIdx.x;
    int lo = t * SCAN_CHUNK;
    int hi = min(lo + SCAN_CHUNK, N_NODES);
    int mysum = 0;
    for (int i = lo; i < hi; i++) mysum += cnt[i];
    sPart[t] = mysum;
    __syncthreads();
    // Hillis-Steele inclusive scan over 1024 partials
    for (int off = 1; off < SCAN_THREADS; off <<= 1) {
        int v = (t >= off) ? sPart[t - off] : 0;
        __syncthreads();
        sPart[t] += v;
        __syncthreads();
    }
    int running = sPart[t] - mysum;  // exclusive
    for (int i = lo; i < hi; i++) {
        base[i] = running;
        cursor[i] = running;
        running += cnt[i];
    }
    if (t == 0) base[N_NODES] = sPart[SCAN_THREADS - 1];
}

// Kernel 4: scatter edge sources into per-destination segments
__global__ __launch_bounds__(256) void k_scatter(const int* __restrict__ ei,
                                                 int* __restrict__ cursor,
                                                 int* __restrict__ sorted_src) {
    int e = blockIdx.x * blockDim.x + threadIdx.x;
    if (e >= N_EDGES) return;
    int s = ei[e], d = ei[N_EDGES + e];
    int pos = atomicAdd(&cursor[d], 1);
    sorted_src[pos] = s;
}

// Kernel 5: per-destination aggregation, fused normalize + residual + mean.
// Softmax without max-subtraction (shift-invariant; |v| is O(1) here).
__global__ __launch_bounds__(256) void k_agg(
        const int* __restrict__ base, const int* __restrict__ sorted_src,
        const float* __restrict__ el, const float* __restrict__ er,
        const float* __restrict__ feat, const float* __restrict__ res,
        const float* __restrict__ bias, float* __restrict__ out) {
    int n = blockIdx.x * blockDim.x + threadIdx.x;
    if (n >= N_NODES) return;
    int b = base[n], e = base[n + 1];
    float er0 = er[n * 2 + 0], er1 = er[n * 2 + 1];
    float den0 = 0.f, den1 = 0.f;
    float S[FH];
    #pragma unroll
    for (int k = 0; k < FH; k++) S[k] = 0.f;
    for (int j = b; j < e; j++) {
        int s = sorted_src[j];
        float v0 = el[s * 2 + 0] + er0;
        float v1 = el[s * 2 + 1] + er1;
        v0 = v0 >= 0.f ? v0 : NEG_SLOPE * v0;
        v1 = v1 >= 0.f ? v1 : NEG_SLOPE * v1;
        float w0 = __expf(v0), w1 = __expf(v1);
        den0 += w0; den1 += w1;
        const float4* fp = (const float4*)(feat + (size_t)s * FH);
        float4 f0 = fp[0], f1 = fp[1], f2 = fp[2], f3 = fp[3];
        S[0]  = fmaf(w0, f0.x, S[0]);  S[1]  = fmaf(w0, f0.y, S[1]);
        S[2]  = fmaf(w0, f0.z, S[2]);  S[3]  = fmaf(w0, f0.w, S[3]);
        S[4]  = fmaf(w0, f1.x, S[4]);  S[5]  = fmaf(w0, f1.y, S[5]);
        S[6]  = fmaf(w0, f1.z, S[6]);  S[7]  = fmaf(w0, f1.w, S[7]);
        S[8]  = fmaf(w1, f2.x, S[8]);  S[9]  = fmaf(w1, f2.y, S[9]);
        S[10] = fmaf(w1, f2.z, S[10]); S[11] = fmaf(w1, f2.w, S[11]);
        S[12] = fmaf(w1, f3.x, S[12]); S[13] = fmaf(w1, f3.y, S[13]);
        S[14] = fmaf(w1, f3.z, S[14]); S[15] = fmaf(w1, f3.w, S[15]);
    }
    float inv0 = 1.f / fmaxf(den0, EPSF);
    float inv1 = 1.f / fmaxf(den1, EPSF);
    const float* rr = res + (size_t)n * FH;
    #pragma unroll
    for (int c = 0; c < NC; c++) {
        float r0 = S[c]      * inv0 + rr[c]      + bias[c];
        float r1 = S[NC + c] * inv1 + rr[NC + c] + bias[NC + c];
        out[(size_t)n * NC + c] = 0.5f * (r0 + r1);
    }
}

extern "C" void kernel_launch(void* const* d_in, const int* in_sizes, int n_in,
                              void* d_out, int out_size, void* d_ws, size_t ws_size,
                              hipStream_t stream) {
    const float* x      = (const float*)d_in[0];
    const int*   ei     = (const int*)d_in[1];
    const float* W      = (const float*)d_in[2];
    const float* attn_l = (const float*)d_in[3];
    const float* attn_r = (const float*)d_in[4];
    const float* bias   = (const float*)d_in[5];
    const float* Wres   = (const float*)d_in[6];
    float* out = (float*)d_out;

    char* ws = (char*)d_ws;
    const size_t szNF = (size_t)N_NODES * FH * sizeof(float);     // 6.4 MB
    const size_t szNH = (size_t)N_NODES * HEADS * sizeof(float);  // 0.8 MB
    const size_t szCnt = (size_t)(N_NODES + 1) * sizeof(int);     // ~0.4 MB
    float* feat       = (float*)(ws);
    float* res        = (float*)(ws + szNF);
    float* el         = (float*)(ws + 2 * szNF);
    float* er         = (float*)(ws + 2 * szNF + szNH);
    int*   cnt        = (int*)  (ws + 2 * szNF + 2 * szNH);
    int*   base       = (int*)  (ws + 2 * szNF + 2 * szNH + szCnt);
    int*   cursor     = (int*)  (ws + 2 * szNF + 2 * szNH + 2 * szCnt);
    int*   sorted_src = (int*)  (ws + 2 * szNF + 2 * szNH + 3 * szCnt);

    hipMemsetAsync(cnt, 0, (size_t)N_NODES * sizeof(int), stream);
    k_node<<<(N_NODES + 255) / 256, 256, 0, stream>>>(x, W, Wres, attn_l, attn_r,
                                                      feat, res, el, er);
    k_hist<<<(N_EDGES + 255) / 256, 256, 0, stream>>>(ei, cnt);
    k_scan<<<1, SCAN_THREADS, 0, stream>>>(cnt, base, cursor);
    k_scatter<<<(N_EDGES + 255) / 256, 256, 0, stream>>>(ei, cursor, sorted_src);
    k_agg<<<(N_NODES + 255) / 256, 256, 0, stream>>>(base, sorted_src, el, er,
                                                     feat, res, bias, out);
}

// Round 3
// 396.455 us; speedup vs baseline: 8.2200x; 1.9364x over previous
//
#include <hip/hip_runtime.h>
#include <math.h>

#define N_NODES 100000
#define N_EDGES 3200000
#define IN_FEAT 256
#define HEADS 2
#define NC 8
#define FH 16               // HEADS*NC
#define NEG_SLOPE 0.2f
#define EPSF 1e-15f

#define SCAN_BLK 1024
#define NBLK ((N_NODES + SCAN_BLK - 1) / SCAN_BLK)   // 98

// ---------------------------------------------------------------------------
// Kernel 1: per-node logmap0 + feat/res/el/er.  ONE pass over x using
// linearity: logmap0(x) = scale*x  =>  h@W = scale*(x@W).
// W and Wres staged transposed in LDS, read as float4 (broadcast b128).
// 2 nodes per thread to amortize LDS reads.
__global__ __launch_bounds__(256) void k_node(
        const float* __restrict__ x, const float* __restrict__ W,
        const float* __restrict__ Wres, const float* __restrict__ attn_l,
        const float* __restrict__ attn_r,
        float* __restrict__ feat, float* __restrict__ res,
        float* __restrict__ el, float* __restrict__ er) {
    __shared__ float sWT[2 * FH][IN_FEAT];   // 32 x 256 floats = 32 KB
    int t = threadIdx.x;
    for (int idx = t; idx < 2 * FH * IN_FEAT; idx += 256) {
        int k = idx & 31, r = idx >> 5;
        sWT[k][r] = (k < FH) ? W[r * FH + k] : Wres[r * FH + (k - FH)];
    }
    __syncthreads();

    int n0 = blockIdx.x * 512 + t;
    int n1 = n0 + 256;
    bool v0 = n0 < N_NODES, v1 = n1 < N_NODES;
    int m0 = v0 ? n0 : 0, m1 = v1 ? n1 : 0;
    const float* xr0 = x + (size_t)m0 * IN_FEAT;
    const float* xr1 = x + (size_t)m1 * IN_FEAT;

    float acc0[2 * FH], acc1[2 * FH];
    #pragma unroll
    for (int k = 0; k < 2 * FH; k++) { acc0[k] = 0.f; acc1[k] = 0.f; }
    float ss0 = 0.f, ss1 = 0.f;

    for (int r = 0; r < IN_FEAT; r += 4) {
        float4 a = *(const float4*)(xr0 + r);
        float4 b = *(const float4*)(xr1 + r);
        ss0 += a.x * a.x + a.y * a.y + a.z * a.z + a.w * a.w;
        ss1 += b.x * b.x + b.y * b.y + b.z * b.z + b.w * b.w;
        #pragma unroll
        for (int k = 0; k < 2 * FH; k++) {
            float4 w = *(const float4*)&sWT[k][r];
            acc0[k] = fmaf(a.x, w.x, fmaf(a.y, w.y, fmaf(a.z, w.z, fmaf(a.w, w.w, acc0[k]))));
            acc1[k] = fmaf(b.x, w.x, fmaf(b.y, w.y, fmaf(b.z, w.z, fmaf(b.w, w.w, acc1[k]))));
        }
    }

    float al[FH], ar[FH];
    #pragma unroll
    for (int k = 0; k < FH; k++) { al[k] = attn_l[k]; ar[k] = attn_r[k]; }

    #pragma unroll
    for (int pick = 0; pick < 2; pick++) {
        bool valid = pick ? v1 : v0;
        if (!valid) continue;
        int n = pick ? n1 : n0;
        float ss = pick ? ss1 : ss0;
        float* acc = pick ? acc1 : acc0;
        float norm = fmaxf(sqrtf(ss), EPSF);
        float z = fminf(norm, 1.f - 1e-7f);
        float at = 0.5f * (log1pf(z) - log1pf(-z));   // artanh(clip)
        float scale = at / norm;
        size_t o = (size_t)n * FH;
        float elh0 = 0.f, elh1 = 0.f, erh0 = 0.f, erh1 = 0.f;
        float f[FH], rr[FH];
        #pragma unroll
        for (int k = 0; k < FH; k++) {
            f[k]  = scale * acc[k];
            rr[k] = scale * acc[FH + k];
        }
        #pragma unroll
        for (int c = 0; c < NC; c++) {
            elh0 = fmaf(f[c], al[c], elh0);
            erh0 = fmaf(f[c], ar[c], erh0);
            elh1 = fmaf(f[NC + c], al[NC + c], elh1);
            erh1 = fmaf(f[NC + c], ar[NC + c], erh1);
        }
        #pragma unroll
        for (int k = 0; k < FH; k += 4)
            *(float4*)(feat + o + k) = make_float4(f[k], f[k+1], f[k+2], f[k+3]);
        #pragma unroll
        for (int k = 0; k < FH; k += 4)
            *(float4*)(res + o + k) = make_float4(rr[k], rr[k+1], rr[k+2], rr[k+3]);
        *(float2*)(el + n * 2) = make_float2(elh0, elh1);
        *(float2*)(er + n * 2) = make_float2(erh0, erh1);
    }
}

// ---------------------------------------------------------------------------
// Kernel 2: degree histogram + per-edge ticket (rank within destination).
__global__ __launch_bounds__(256) void k_ticket(const int* __restrict__ ei,
                                                int* __restrict__ cnt,
                                                int* __restrict__ ticket) {
    int e4 = (blockIdx.x * blockDim.x + threadIdx.x) * 4;
    if (e4 >= N_EDGES) return;
    int4 d = *(const int4*)(ei + N_EDGES + e4);
    int4 tk;
    tk.x = atomicAdd(&cnt[d.x], 1);
    tk.y = atomicAdd(&cnt[d.y], 1);
    tk.z = atomicAdd(&cnt[d.z], 1);
    tk.w = atomicAdd(&cnt[d.w], 1);
    *(int4*)(ticket + e4) = tk;
}

// ---------------------------------------------------------------------------
// Scan (3 coalesced kernels): A = per-1024-block sums, B = scan of 98 sums,
// C = per-block scan + write base[].
__global__ __launch_bounds__(256) void k_scanA(const int* __restrict__ cnt,
                                               int* __restrict__ bsum) {
    __shared__ int sm[256];
    int t = threadIdx.x;
    int i0 = blockIdx.x * SCAN_BLK + t * 4;
    int s = 0;
    if (i0 + 3 < N_NODES) {
        int4 v = *(const int4*)(cnt + i0);
        s = v.x + v.y + v.z + v.w;
    } else {
        for (int i = i0; i < N_NODES && i < i0 + 4; i++) s += cnt[i];
    }
    sm[t] = s; __syncthreads();
    for (int off = 128; off > 0; off >>= 1) {
        if (t < off) sm[t] += sm[t + off];
        __syncthreads();
    }
    if (t == 0) bsum[blockIdx.x] = sm[0];
}

__global__ __launch_bounds__(128) void k_scanB(const int* __restrict__ bsum,
                                               int* __restrict__ boff,
                                               int* __restrict__ base) {
    __shared__ int sm[128];
    int t = threadIdx.x;
    int v = (t < NBLK) ? bsum[t] : 0;
    sm[t] = v; __syncthreads();
    for (int off = 1; off < 128; off <<= 1) {
        int u = (t >= off) ? sm[t - off] : 0;
        __syncthreads();
        sm[t] += u;
        __syncthreads();
    }
    if (t < NBLK) boff[t] = sm[t] - v;        // exclusive
    if (t == 127) base[N_NODES] = sm[127];    // total = N_EDGES
}

__global__ __launch_bounds__(256) void k_scanC(const int* __restrict__ cnt,
                                               const int* __restrict__ boff,
                                               int* __restrict__ base) {
    __shared__ int sm[256];
    int t = threadIdx.x;
    int i0 = blockIdx.x * SCAN_BLK + t * 4;
    int c0 = 0, c1 = 0, c2 = 0, c3 = 0;
    if (i0 + 3 < N_NODES) {
        int4 v = *(const int4*)(cnt + i0);
        c0 = v.x; c1 = v.y; c2 = v.z; c3 = v.w;
    } else {
        if (i0 + 0 < N_NODES) c0 = cnt[i0 + 0];
        if (i0 + 1 < N_NODES) c1 = cnt[i0 + 1];
        if (i0 + 2 < N_NODES) c2 = cnt[i0 + 2];
        if (i0 + 3 < N_NODES) c3 = cnt[i0 + 3];
    }
    int s = c0 + c1 + c2 + c3;
    sm[t] = s; __syncthreads();
    for (int off = 1; off < 256; off <<= 1) {
        int u = (t >= off) ? sm[t - off] : 0;
        __syncthreads();
        sm[t] += u;
        __syncthreads();
    }
    int run = boff[blockIdx.x] + sm[t] - s;   // exclusive start for this thread
    int b0 = run, b1 = b0 + c0, b2 = b1 + c1, b3 = b2 + c2;
    if (i0 + 3 < N_NODES) {
        *(int4*)(base + i0) = make_int4(b0, b1, b2, b3);
    } else {
        if (i0 + 0 < N_NODES) base[i0 + 0] = b0;
        if (i0 + 1 < N_NODES) base[i0 + 1] = b1;
        if (i0 + 2 < N_NODES) base[i0 + 2] = b2;
        if (i0 + 3 < N_NODES) base[i0 + 3] = b3;
    }
}

// ---------------------------------------------------------------------------
// Kernel 4: atomic-free scatter — pure blind stores.
__global__ __launch_bounds__(256) void k_scatter(const int* __restrict__ ei,
                                                 const int* __restrict__ base,
                                                 const int* __restrict__ ticket,
                                                 int* __restrict__ sorted_src) {
    int e4 = (blockIdx.x * blockDim.x + threadIdx.x) * 4;
    if (e4 >= N_EDGES) return;
    int4 s  = *(const int4*)(ei + e4);
    int4 d  = *(const int4*)(ei + N_EDGES + e4);
    int4 tk = *(const int4*)(ticket + e4);
    sorted_src[base[d.x] + tk.x] = s.x;
    sorted_src[base[d.y] + tk.y] = s.y;
    sorted_src[base[d.z] + tk.z] = s.z;
    sorted_src[base[d.w] + tk.w] = s.w;
}

// ---------------------------------------------------------------------------
// Kernel 5: per-destination aggregation (softmax w/o max-shift), fused
// normalize + residual + bias + head-mean.  Unrolled by 2 for gather ILP.
__global__ __launch_bounds__(256) void k_agg(
        const int* __restrict__ base, const int* __restrict__ sorted_src,
        const float* __restrict__ el, const float* __restrict__ er,
        const float* __restrict__ feat, const float* __restrict__ res,
        const float* __restrict__ bias, float* __restrict__ out) {
    int n = blockIdx.x * blockDim.x + threadIdx.x;
    if (n >= N_NODES) return;
    int b = base[n], e = base[n + 1];
    float2 ern = *(const float2*)(er + n * 2);
    float den0 = 0.f, den1 = 0.f;
    float S[FH];
    #pragma unroll
    for (int k = 0; k < FH; k++) S[k] = 0.f;

    int j = b;
    for (; j + 2 <= e; j += 2) {
        int s0 = sorted_src[j], s1 = sorted_src[j + 1];
        float2 ea = *(const float2*)(el + s0 * 2);
        float2 eb = *(const float2*)(el + s1 * 2);
        const float4* fpa = (const float4*)(feat + (size_t)s0 * FH);
        const float4* fpb = (const float4*)(feat + (size_t)s1 * FH);
        float4 a0 = fpa[0], a1 = fpa[1], a2 = fpa[2], a3 = fpa[3];
        float4 b0 = fpb[0], b1 = fpb[1], b2 = fpb[2], b3 = fpb[3];
        float va0 = ea.x + ern.x, va1 = ea.y + ern.y;
        float vb0 = eb.x + ern.x, vb1 = eb.y + ern.y;
        va0 = va0 >= 0.f ? va0 : NEG_SLOPE * va0;
        va1 = va1 >= 0.f ? va1 : NEG_SLOPE * va1;
        vb0 = vb0 >= 0.f ? vb0 : NEG_SLOPE * vb0;
        vb1 = vb1 >= 0.f ? vb1 : NEG_SLOPE * vb1;
        float wa0 = __expf(va0), wa1 = __expf(va1);
        float wb0 = __expf(vb0), wb1 = __expf(vb1);
        den0 += wa0 + wb0; den1 += wa1 + wb1;
        S[0]  = fmaf(wa0, a0.x, fmaf(wb0, b0.x, S[0]));
        S[1]  = fmaf(wa0, a0.y, fmaf(wb0, b0.y, S[1]));
        S[2]  = fmaf(wa0, a0.z, fmaf(wb0, b0.z, S[2]));
        S[3]  = fmaf(wa0, a0.w, fmaf(wb0, b0.w, S[3]));
        S[4]  = fmaf(wa0, a1.x, fmaf(wb0, b1.x, S[4]));
        S[5]  = fmaf(wa0, a1.y, fmaf(wb0, b1.y, S[5]));
        S[6]  = fmaf(wa0, a1.z, fmaf(wb0, b1.z, S[6]));
        S[7]  = fmaf(wa0, a1.w, fmaf(wb0, b1.w, S[7]));
        S[8]  = fmaf(wa1, a2.x, fmaf(wb1, b2.x, S[8]));
        S[9]  = fmaf(wa1, a2.y, fmaf(wb1, b2.y, S[9]));
        S[10] = fmaf(wa1, a2.z, fmaf(wb1, b2.z, S[10]));
        S[11] = fmaf(wa1, a2.w, fmaf(wb1, b2.w, S[11]));
        S[12] = fmaf(wa1, a3.x, fmaf(wb1, b3.x, S[12]));
        S[13] = fmaf(wa1, a3.y, fmaf(wb1, b3.y, S[13]));
        S[14] = fmaf(wa1, a3.z, fmaf(wb1, b3.z, S[14]));
        S[15] = fmaf(wa1, a3.w, fmaf(wb1, b3.w, S[15]));
    }
    if (j < e) {
        int s0 = sorted_src[j];
        float2 ea = *(const float2*)(el + s0 * 2);
        float v0 = ea.x + ern.x, v1 = ea.y + ern.y;
        v0 = v0 >= 0.f ? v0 : NEG_SLOPE * v0;
        v1 = v1 >= 0.f ? v1 : NEG_SLOPE * v1;
        float w0 = __expf(v0), w1 = __expf(v1);
        den0 += w0; den1 += w1;
        const float4* fp = (const float4*)(feat + (size_t)s0 * FH);
        float4 f0 = fp[0], f1 = fp[1], f2 = fp[2], f3 = fp[3];
        S[0]  = fmaf(w0, f0.x, S[0]);  S[1]  = fmaf(w0, f0.y, S[1]);
        S[2]  = fmaf(w0, f0.z, S[2]);  S[3]  = fmaf(w0, f0.w, S[3]);
        S[4]  = fmaf(w0, f1.x, S[4]);  S[5]  = fmaf(w0, f1.y, S[5]);
        S[6]  = fmaf(w0, f1.z, S[6]);  S[7]  = fmaf(w0, f1.w, S[7]);
        S[8]  = fmaf(w1, f2.x, S[8]);  S[9]  = fmaf(w1, f2.y, S[9]);
        S[10] = fmaf(w1, f2.z, S[10]); S[11] = fmaf(w1, f2.w, S[11]);
        S[12] = fmaf(w1, f3.x, S[12]); S[13] = fmaf(w1, f3.y, S[13]);
        S[14] = fmaf(w1, f3.z, S[14]); S[15] = fmaf(w1, f3.w, S[15]);
    }

    float inv0 = 1.f / fmaxf(den0, EPSF);
    float inv1 = 1.f / fmaxf(den1, EPSF);
    const float* rr = res + (size_t)n * FH;
    #pragma unroll
    for (int c = 0; c < NC; c += 4) {
        float4 r0 = *(const float4*)(rr + c);
        float4 r1 = *(const float4*)(rr + NC + c);
        float4 o;
        o.x = 0.5f * ((S[c+0] * inv0 + r0.x + bias[c+0]) + (S[NC+c+0] * inv1 + r1.x + bias[NC+c+0]));
        o.y = 0.5f * ((S[c+1] * inv0 + r0.y + bias[c+1]) + (S[NC+c+1] * inv1 + r1.y + bias[NC+c+1]));
        o.z = 0.5f * ((S[c+2] * inv0 + r0.z + bias[c+2]) + (S[NC+c+2] * inv1 + r1.z + bias[NC+c+2]));
        o.w = 0.5f * ((S[c+3] * inv0 + r0.w + bias[c+3]) + (S[NC+c+3] * inv1 + r1.w + bias[NC+c+3]));
        *(float4*)(out + (size_t)n * NC + c) = o;
    }
}

extern "C" void kernel_launch(void* const* d_in, const int* in_sizes, int n_in,
                              void* d_out, int out_size, void* d_ws, size_t ws_size,
                              hipStream_t stream) {
    const float* x      = (const float*)d_in[0];
    const int*   ei     = (const int*)d_in[1];
    const float* W      = (const float*)d_in[2];
    const float* attn_l = (const float*)d_in[3];
    const float* attn_r = (const float*)d_in[4];
    const float* bias   = (const float*)d_in[5];
    const float* Wres   = (const float*)d_in[6];
    float* out = (float*)d_out;

    char* ws = (char*)d_ws;
    const size_t szNF  = (size_t)N_NODES * FH * sizeof(float);   // 6,400,000
    const size_t szNH  = (size_t)N_NODES * HEADS * sizeof(float);//   800,000
    const size_t szCnt = 401408;                                  // padded
    const size_t szBase= 400016;
    const size_t szB   = 512;
    size_t off = 0;
    float* feat       = (float*)(ws + off); off += szNF;
    float* res        = (float*)(ws + off); off += szNF;
    float* el         = (float*)(ws + off); off += szNH;
    float* er         = (float*)(ws + off); off += szNH;
    int*   cnt        = (int*)  (ws + off); off += szCnt;
    int*   base       = (int*)  (ws + off); off += szBase;
    int*   bsum       = (int*)  (ws + off); off += szB;
    int*   boff       = (int*)  (ws + off); off += szB;
    int*   ticket     = (int*)  (ws + off); off += (size_t)N_EDGES * sizeof(int);
    int*   sorted_src = (int*)  (ws + off); off += (size_t)N_EDGES * sizeof(int);

    hipMemsetAsync(cnt, 0, (size_t)N_NODES * sizeof(int), stream);
    k_node<<<(N_NODES + 511) / 512, 256, 0, stream>>>(x, W, Wres, attn_l, attn_r,
                                                      feat, res, el, er);
    k_ticket<<<(N_EDGES / 4 + 255) / 256, 256, 0, stream>>>(ei, cnt, ticket);
    k_scanA<<<NBLK, 256, 0, stream>>>(cnt, bsum);
    k_scanB<<<1, 128, 0, stream>>>(bsum, boff, base);
    k_scanC<<<NBLK, 256, 0, stream>>>(cnt, boff, base);
    k_scatter<<<(N_EDGES / 4 + 255) / 256, 256, 0, stream>>>(ei, base, ticket,
                                                             sorted_src);
    k_agg<<<(N_NODES + 255) / 256, 256, 0, stream>>>(base, sorted_src, el, er,
                                                     feat, res, bias, out);
}